// Round 6
// baseline (175.243 us; speedup 1.0000x reference)
//
#include <hip/hip_runtime.h>
#include <hip/hip_bf16.h>
#include <math.h>

// ---------------------------------------------------------------------------
// Sketched CNN-MNIST forward, MFMA end-to-end.
// conv1: MFMA, taps t=ki*6+kj (K=30 pad 32); ALL lanes read even-aligned b32
//        pairs; odd-column output rows use a kj-shifted weight matrix wc1s
//        (second MFMA) and pooling picks alternating accumulator regs.
// conv2: channel-last h1 (stride-40), 25 tap-GEMMs K=ic=32, 4 img/block,
//        8 waves, 3 blocks/CU (LDS 51.4 KB).
// fc1:   split-N grid (B/16, 2), 1024 thr, A-tile in LDS, h3 -> global.
// fc2:   separate kernel, fc2w staged in LDS, shuffle-reduce + log_softmax.
// ---------------------------------------------------------------------------

typedef __attribute__((ext_vector_type(8))) short bf16x8;
typedef __attribute__((ext_vector_type(4))) float f32x4;

static __device__ inline ushort f2bfu(float v) {
    union { __hip_bfloat16 h; ushort u; } cv;
    cv.h = __float2bfloat16(v);
    return cv.u;
}

// ws layout (bytes):
//   wc1b bf16 [32 oc][32 t]  t=ki*6+kj       [0,       2048)
//   wc1s bf16 [32 oc][32 t]  kj-shifted      [2048,    4096)
//   wc2b bf16 [64 oc][25 tap][32 ic]         [4096,    106496)
//   W3   bf16 [512][1024]                    [106496,  1155072)
//   h2   bf16 [B][1024]                      [1155072, +B*2048)
//   h3   f32  [B][512]                       [...,     +B*2048)

__global__ __launch_bounds__(256)
void k_reconstruct(const float* __restrict__ w1, const float* __restrict__ w2,
                   const float* __restrict__ w3,
                   const int* __restrict__ hi1, const int* __restrict__ hi2,
                   const int* __restrict__ hi3,
                   const float* __restrict__ s1, const float* __restrict__ s2,
                   const float* __restrict__ s3,
                   __hip_bfloat16* __restrict__ wc1b,
                   __hip_bfloat16* __restrict__ wc1s,
                   __hip_bfloat16* __restrict__ wc2b,
                   __hip_bfloat16* __restrict__ W3) {
    int i = blockIdx.x * blockDim.x + threadIdx.x;
    if (i < 1024) {
        int oc = i >> 5, t = i & 31;
        int ki = (t * 43) >> 8;            // t / 6
        int kj = t - 6 * ki;
        float v = 0.f;
        if (ki < 5 && kj < 5) {
            int f = ki * 5 + kj;
            v = w1[oc * 128 + hi1[f]] * s1[f];
        }
        wc1b[i] = __float2bfloat16(v);
    } else if (i < 2048) {                 // kj-shifted conv1 weights
        int j = i - 1024;
        int oc = j >> 5, t = j & 31;
        int ki = (t * 43) >> 8;
        int kj = t - 6 * ki;
        float v = 0.f;
        if (ki < 5 && kj >= 1) {           // kj in 1..5 -> real tap kj-1
            int f = ki * 5 + (kj - 1);
            v = w1[oc * 128 + hi1[f]] * s1[f];
        }
        wc1s[j] = __float2bfloat16(v);
    } else if (i < 53248) {
        int j = i - 2048;
        int oc = j / 800, r = j % 800;
        int tap = r >> 5, ic = r & 31;
        int f = ic * 25 + tap;             // original sketch index
        wc2b[j] = __float2bfloat16(w2[oc * 128 + hi2[f]] * s2[f]);
    } else if (i < 577536) {
        int j = i - 53248;
        int r = j >> 10, k = j & 1023;
        W3[j] = __float2bfloat16(w3[r * 128 + hi3[k]] * s3[k]);
    }
}

// 4 images per block, 8 waves, 3 blocks/CU.
__global__ __launch_bounds__(512, 6)
void k_conv(const float* __restrict__ x,
            const __hip_bfloat16* __restrict__ wc1b,
            const __hip_bfloat16* __restrict__ wc1s,
            const __hip_bfloat16* __restrict__ wc2b,
            const float* __restrict__ b1, const float* __restrict__ b2,
            __hip_bfloat16* __restrict__ h2) {
    __shared__ __align__(16) ushort s_xb[4 * 816];        // bf16 images (+pad)
    __shared__ __align__(16) ushort s_h1[4 * 144 * 40];   // [img][pos][ic] stride 40

    const int tid = threadIdx.x;
    const int b0 = blockIdx.x * 4;
    const int wave = tid >> 6, lane = tid & 63;
    const int l15 = lane & 15, quad = lane >> 4;

    // ---- stage 4 images as bf16 (coalesced float4) ----
    {
        const float4* xg = (const float4*)(x + (size_t)b0 * 784);
        for (int i = tid; i < 784; i += 512) {
            float4 v = xg[i];
            int img = i / 196;
            int pos = (i - img * 196) * 4;
            ushort* dst = &s_xb[img * 816 + pos];
            dst[0] = f2bfu(v.x); dst[1] = f2bfu(v.y);
            dst[2] = f2bfu(v.z); dst[3] = f2bfu(v.w);
        }
        if (tid < 128) {                    // zero the pad (read by pad taps, w=0)
            int img = tid >> 5, k = tid & 31;
            s_xb[img * 816 + 784 + k] = 0;
        }
    }

    // conv1 B-fragments (normal + shifted) + biases (tiny, L2-resident)
    bf16x8 bw1[2], bw1s[2];
    float bb1[2];
    #pragma unroll
    for (int nt = 0; nt < 2; ++nt) {
        bw1[nt]  = *(const bf16x8*)((const ushort*)wc1b + (nt * 16 + l15) * 32 + quad * 8);
        bw1s[nt] = *(const bf16x8*)((const ushort*)wc1s + (nt * 16 + l15) * 32 + quad * 8);
        bb1[nt] = b1[nt * 16 + l15];
    }
    __syncthreads();

    // ---- conv1 via MFMA: wave = (img, half). M=576 pool-grouped, N=32 ----
    // All lanes read from even base (col parity dropped); even-parity output
    // rows come from A x bw1, odd-parity rows from A x bw1s. In D, row parity
    // == reg parity, so pool = max(ce[0], co[1], ce[2], co[3]).
    {
        const int img = wave >> 1, half = wave & 1;
        const int sub = l15 & 3;
        const ushort* srcImg = s_xb + img * 816;
        int offr[4];
        #pragma unroll
        for (int r = 0; r < 4; ++r) {
            int t = quad * 8 + 2 * r;          // even
            int row = (t * 43) >> 8;           // t / 6
            int col = t - 6 * row;             // even
            offr[r] = row * 28 + col;          // even
        }
        #pragma unroll
        for (int ii = 0; ii < 18; ++ii) {
            const int i = half * 18 + ii;
            const int pb = 4 * i + (l15 >> 2);
            const int pi = (pb * 171) >> 11;   // pb / 12
            const int pj = pb - 12 * pi;
            const int base_e = (2 * pi + (sub >> 1)) * 28 + 2 * pj;   // even
            const ushort* p0 = srcImg + base_e;
            union { bf16x8 v; uint u[4]; } A;
            A.u[0] = *(const uint*)(p0 + offr[0]);
            A.u[1] = *(const uint*)(p0 + offr[1]);
            A.u[2] = *(const uint*)(p0 + offr[2]);
            A.u[3] = *(const uint*)(p0 + offr[3]);
            f32x4 z = {0.f, 0.f, 0.f, 0.f};
            f32x4 ce0 = __builtin_amdgcn_mfma_f32_16x16x32_bf16(A.v, bw1[0],  z, 0, 0, 0);
            f32x4 co0 = __builtin_amdgcn_mfma_f32_16x16x32_bf16(A.v, bw1s[0], z, 0, 0, 0);
            f32x4 ce1 = __builtin_amdgcn_mfma_f32_16x16x32_bf16(A.v, bw1[1],  z, 0, 0, 0);
            f32x4 co1 = __builtin_amdgcn_mfma_f32_16x16x32_bf16(A.v, bw1s[1], z, 0, 0, 0);
            const int pbo = 4 * i + quad;
            float m0 = fmaxf(fmaxf(ce0[0], co0[1]), fmaxf(ce0[2], co0[3]));
            float m1 = fmaxf(fmaxf(ce1[0], co1[1]), fmaxf(ce1[2], co1[3]));
            s_h1[(img * 144 + pbo) * 40 + l15]      = f2bfu(fmaxf(m0 + bb1[0], 0.f));
            s_h1[(img * 144 + pbo) * 40 + 16 + l15] = f2bfu(fmaxf(m1 + bb1[1], 0.f));
        }
    }
    __syncthreads();

    // ---- conv2: 25 tap-GEMMs, K=ic=32; wave = (pool-row, n-half), 4 images ----
    const int pr = wave >> 1, nh = wave & 1;
    const int sub2 = l15 & 3;
    const int ci2 = 2 * pr + (sub2 >> 1);
    const int cj2 = 2 * (l15 >> 2) + (sub2 & 1);
    const int apos = (ci2 * 12 + cj2) * 40 + quad * 8;
    const ushort* bP = (const ushort*)wc2b + quad * 8;

    f32x4 acc[4][2];                       // [img][ntl]
    float bb2[2];
    #pragma unroll
    for (int ntl = 0; ntl < 2; ++ntl) {
        bb2[ntl] = b2[(nh * 2 + ntl) * 16 + l15];
        #pragma unroll
        for (int img = 0; img < 4; ++img)
            acc[img][ntl] = (f32x4){0.f, 0.f, 0.f, 0.f};
    }

    #pragma unroll
    for (int tap = 0; tap < 25; ++tap) {
        const int ki = tap / 5, kj = tap % 5;          // compile-time
        bf16x8 a[4];
        #pragma unroll
        for (int img = 0; img < 4; ++img)
            a[img] = *(const bf16x8*)&s_h1[img * 5760 + apos + (ki * 12 + kj) * 40];
        #pragma unroll
        for (int ntl = 0; ntl < 2; ++ntl) {
            bf16x8 bf = *(const bf16x8*)(bP + ((nh * 2 + ntl) * 16 + l15) * 800 + tap * 32);
            #pragma unroll
            for (int img = 0; img < 4; ++img)
                acc[img][ntl] = __builtin_amdgcn_mfma_f32_16x16x32_bf16(
                    a[img], bf, acc[img][ntl], 0, 0, 0);
        }
    }

    // D rows m = quad*4+r -> (pool row = pr, pool col = quad), max over r
    #pragma unroll
    for (int img = 0; img < 4; ++img)
        #pragma unroll
        for (int ntl = 0; ntl < 2; ++ntl) {
            f32x4 c = acc[img][ntl];
            float m = fmaxf(fmaxf(c[0], c[1]), fmaxf(c[2], c[3]));
            float v = fmaxf(m + bb2[ntl], 0.f);
            h2[(size_t)(b0 + img) * 1024 + ((nh * 2 + ntl) * 16 + l15) * 16 + pr * 4 + quad] =
                __float2bfloat16(v);
        }
}

// fc1: h3 = relu(h2 @ W3^T + b3). Grid (B/16, 2); 1024 thr = 16 waves;
// wave = 16-col strip of this block's 256-col half. A-tile staged in LDS.
__global__ __launch_bounds__(1024, 8)
void k_fc1(const __hip_bfloat16* __restrict__ A, const __hip_bfloat16* __restrict__ Bw,
           const float* __restrict__ b3, float* __restrict__ h3) {
    __shared__ __align__(16) ushort s_A[16 * 1032];   // +8 pad per row

    const int tid = threadIdx.x;
    const int wave = tid >> 6, lane = tid & 63;
    const int l15 = lane & 15, quad = lane >> 4;
    const int mBase = blockIdx.x * 16;
    const int nBase = blockIdx.y * 256 + wave * 16;

    // stage A row `wave` into LDS (64 lanes x 32 B = 2 KB row)
    {
        const uint4* g = (const uint4*)(A + (size_t)(mBase + wave) * 1024);
        uint4 v0 = g[lane * 2], v1 = g[lane * 2 + 1];
        uint4* d = (uint4*)&s_A[wave * 1032 + lane * 16];
        d[0] = v0; d[1] = v1;
    }
    __syncthreads();

    f32x4 acc = {0.f, 0.f, 0.f, 0.f};
    const ushort* aP = &s_A[l15 * 1032 + quad * 8];
    const __hip_bfloat16* bP = Bw + (size_t)(nBase + l15) * 1024 + quad * 8;
    #pragma unroll 8
    for (int kt = 0; kt < 32; ++kt) {
        bf16x8 a = *(const bf16x8*)(aP + kt * 32);
        bf16x8 b = *(const bf16x8*)(bP + kt * 32);
        acc = __builtin_amdgcn_mfma_f32_16x16x32_bf16(a, b, acc, 0, 0, 0);
    }

    const int col = nBase + l15;
    const float bb = b3[col];
    #pragma unroll
    for (int r = 0; r < 4; ++r)
        h3[(size_t)(mBase + quad * 4 + r) * 512 + col] = fmaxf(acc[r] + bb, 0.f);
}

// fc2 + log_softmax: 16 images/block, fc2w staged in LDS, 16-lane reduce.
__global__ __launch_bounds__(256, 8)
void k_fc2(const float* __restrict__ h3, const float* __restrict__ fc2w,
           const float* __restrict__ fc2b, float* __restrict__ out) {
    __shared__ float s_w[5120];            // [10][512]

    const int tid = threadIdx.x;
    for (int i = tid; i < 1280; i += 256)
        ((float4*)s_w)[i] = ((const float4*)fc2w)[i];
    __syncthreads();

    const int m = tid >> 4, t16 = tid & 15;
    const int img = blockIdx.x * 16 + m;

    float acc[10];
    #pragma unroll
    for (int c = 0; c < 10; ++c) acc[c] = 0.f;
    #pragma unroll
    for (int kb = 0; kb < 8; ++kb) {
        const int k = kb * 64 + t16 * 4;
        float4 h = *(const float4*)&h3[(size_t)img * 512 + k];
        #pragma unroll
        for (int c = 0; c < 10; ++c) {
            float4 w = *(const float4*)&s_w[c * 512 + k];
            acc[c] += h.x * w.x + h.y * w.y + h.z * w.z + h.w * w.w;
        }
    }
    #pragma unroll
    for (int c = 0; c < 10; ++c) {
        acc[c] += __shfl_down(acc[c], 8, 16);
        acc[c] += __shfl_down(acc[c], 4, 16);
        acc[c] += __shfl_down(acc[c], 2, 16);
        acc[c] += __shfl_down(acc[c], 1, 16);
    }
    if (t16 == 0) {
        float l[10], mx = -1e30f;
        #pragma unroll
        for (int c = 0; c < 10; ++c) { l[c] = acc[c] + fc2b[c]; mx = fmaxf(mx, l[c]); }
        float sum = 0.f;
        #pragma unroll
        for (int c = 0; c < 10; ++c) sum += expf(l[c] - mx);
        float lse = mx + logf(sum);
        #pragma unroll
        for (int c = 0; c < 10; ++c)
            out[(size_t)img * 10 + c] = l[c] - lse;
    }
}

extern "C" void kernel_launch(void* const* d_in, const int* in_sizes, int n_in,
                              void* d_out, int out_size, void* d_ws, size_t ws_size,
                              hipStream_t stream) {
    const float* x    = (const float*)d_in[0];
    const int*   hi1  = (const int*)d_in[1];
    const int*   hi2  = (const int*)d_in[2];
    const int*   hi3  = (const int*)d_in[3];
    const float* s1   = (const float*)d_in[4];
    const float* s2   = (const float*)d_in[5];
    const float* s3   = (const float*)d_in[6];
    const float* w1   = (const float*)d_in[7];
    const float* b1   = (const float*)d_in[8];
    const float* w2   = (const float*)d_in[9];
    const float* b2   = (const float*)d_in[10];
    const float* w3   = (const float*)d_in[11];
    const float* b3   = (const float*)d_in[12];
    const float* fc2w = (const float*)d_in[13];
    const float* fc2b = (const float*)d_in[14];
    float* out = (float*)d_out;

    const int B = in_sizes[0] / 784;   // 4096

    char* ws = (char*)d_ws;
    __hip_bfloat16* wc1b = (__hip_bfloat16*)(ws + 0);
    __hip_bfloat16* wc1s = (__hip_bfloat16*)(ws + 2048);
    __hip_bfloat16* wc2b = (__hip_bfloat16*)(ws + 4096);
    __hip_bfloat16* W3   = (__hip_bfloat16*)(ws + 106496);
    __hip_bfloat16* h2   = (__hip_bfloat16*)(ws + 1155072);
    float*          h3   = (float*)(ws + 1155072 + (size_t)B * 2048);

    k_reconstruct<<<(577536 + 255) / 256, 256, 0, stream>>>(
        w1, w2, w3, hi1, hi2, hi3, s1, s2, s3, wc1b, wc1s, wc2b, W3);
    k_conv<<<B / 4, 512, 0, stream>>>(x, wc1b, wc1s, wc2b, b1, b2, h2);
    k_fc1<<<dim3(B / 16, 2), 1024, 0, stream>>>(h2, W3, b3, h3);
    k_fc2<<<B / 16, 256, 0, stream>>>(h3, fc2w, fc2b, out);
}